// Round 1
// baseline (577.094 us; speedup 1.0000x reference)
//
#include <hip/hip_runtime.h>
#include <hip/hip_bf16.h>

// Problem constants (B=64, S=2048, H=512)
#define BATCH 64
#define SEQ   2048
#define HID   512
#define ROWS  (BATCH * SEQ)   // 131072

typedef __attribute__((ext_vector_type(8))) short short8;
typedef __attribute__((ext_vector_type(4))) float f32x4;

// ---------- helpers ----------
__device__ inline unsigned int cvt2_bf16(float x, float y) {
    __hip_bfloat162 h = __float22bfloat162_rn(make_float2(x, y));
    union { __hip_bfloat162 h2; unsigned int u; } u;
    u.h2 = h;
    return u.u;  // low 16 bits = x, high 16 = y (little-endian)
}

__device__ inline float fast_tanh(float x) {
    // tanh(x) = 1 - 2/(exp(2x)+1); saturates correctly for |x| large.
    float e = __expf(2.0f * x);
    return 1.0f - 2.0f / (e + 1.0f);
}

// ---------- kernel 1: c[b][k] = attn_b[k] + sum_h fin[b][h] * attn_w[k][H+h] ----------
// grid (16, 64), block 256. 8 lanes cooperate per k.
__global__ void k_fin(const float* __restrict__ fin, const float* __restrict__ attw,
                      const float* __restrict__ attb, float* __restrict__ cbuf) {
    int b  = blockIdx.y;
    int k  = blockIdx.x * 32 + (threadIdx.x >> 3);
    int l8 = threadIdx.x & 7;
    const float* f = fin + b * HID;
    const float* w = attw + (size_t)k * (2 * HID) + HID;
    float s = 0.0f;
    for (int h = l8 * 4; h < HID; h += 32) {
        float4 a  = *(const float4*)(f + h);
        float4 ww = *(const float4*)(w + h);
        s += a.x * ww.x + a.y * ww.y + a.z * ww.z + a.w * ww.w;
    }
    s += __shfl_xor(s, 1);
    s += __shfl_xor(s, 2);
    s += __shfl_xor(s, 4);
    if (l8 == 0) cbuf[b * HID + k] = s + attb[k];
}

// ---------- kernel 2: fused energy GEMM + tanh + v-dot -> partial scores ----------
// ee[s][k] = sum_h enc[s][h] * w_enc[k][h]  (M=131072, N=512, K=512)
// scores[s] += sum_k tanh(ee + c[b][k]) * v[k]   (atomic across 4 n-tile blocks)
// Block: 256 threads (4 waves, 2x2), tile 128(M) x 128(N), BK=64.
#define BK  64
#define LDA 72   // BK + 8 pad (bf16 elems) to break bank aliasing

__global__ __launch_bounds__(256) void k_energy(
        const float* __restrict__ enc, const float* __restrict__ attw,
        const float* __restrict__ cbuf, const float* __restrict__ vw,
        float* __restrict__ scores) {
    __shared__ __align__(16) unsigned short As[128 * LDA];
    __shared__ __align__(16) unsigned short Bs[128 * LDA];

    const int nTile = blockIdx.x * 128;     // k-dim tile (0..511)
    const int sRow  = blockIdx.y * 128;     // global row (b*S + s)
    const int bIdx  = sRow >> 11;           // / SEQ

    const int t    = threadIdx.x;
    const int lane = t & 63;
    const int wave = t >> 6;
    const int wm   = wave >> 1;             // 0..1
    const int wn   = wave & 1;              // 0..1
    const int l16  = lane & 15;
    const int q    = lane >> 4;             // 0..3

    // staging coords: 8 threads per 64-float row segment
    const int tr = t >> 3;                  // 0..31
    const int tc = (t & 7) * 8;             // 0..56

    f32x4 acc[4][4];
    #pragma unroll
    for (int i = 0; i < 4; ++i)
        #pragma unroll
        for (int j = 0; j < 4; ++j)
            acc[i][j] = (f32x4){0.f, 0.f, 0.f, 0.f};

    for (int h0 = 0; h0 < HID; h0 += BK) {
        // ---- stage A (enc rows) and B (w_enc rows), fp32 -> bf16 ----
        #pragma unroll
        for (int i = 0; i < 4; ++i) {
            int row = tr + i * 32;
            const float* gA = enc + (size_t)(sRow + row) * HID + h0 + tc;
            float4 a0 = *(const float4*)gA;
            float4 a1 = *(const float4*)(gA + 4);
            uint4 pa;
            pa.x = cvt2_bf16(a0.x, a0.y);
            pa.y = cvt2_bf16(a0.z, a0.w);
            pa.z = cvt2_bf16(a1.x, a1.y);
            pa.w = cvt2_bf16(a1.z, a1.w);
            *(uint4*)(&As[row * LDA + tc]) = pa;

            const float* gB = attw + (size_t)(nTile + row) * (2 * HID) + h0 + tc;
            float4 b0 = *(const float4*)gB;
            float4 b1 = *(const float4*)(gB + 4);
            uint4 pb;
            pb.x = cvt2_bf16(b0.x, b0.y);
            pb.y = cvt2_bf16(b0.z, b0.w);
            pb.z = cvt2_bf16(b1.x, b1.y);
            pb.w = cvt2_bf16(b1.z, b1.w);
            *(uint4*)(&Bs[row * LDA + tc]) = pb;
        }
        __syncthreads();

        // ---- MFMA over this K-slab ----
        #pragma unroll
        for (int kk = 0; kk < BK; kk += 32) {
            short8 af[4], bf[4];
            #pragma unroll
            for (int i = 0; i < 4; ++i)
                af[i] = *(const short8*)(&As[(wm * 64 + i * 16 + l16) * LDA + kk + q * 8]);
            #pragma unroll
            for (int j = 0; j < 4; ++j)
                bf[j] = *(const short8*)(&Bs[(wn * 64 + j * 16 + l16) * LDA + kk + q * 8]);
            #pragma unroll
            for (int i = 0; i < 4; ++i)
                #pragma unroll
                for (int j = 0; j < 4; ++j)
                    acc[i][j] = __builtin_amdgcn_mfma_f32_16x16x32_bf16(
                        af[i], bf[j], acc[i][j], 0, 0, 0);
        }
        __syncthreads();
    }

    // ---- epilogue: tanh, dot with v, reduce over 16 lanes, atomic to scores ----
    // C/D mapping: col = lane&15, row = q*4 + reg
    #pragma unroll
    for (int i = 0; i < 4; ++i) {
        #pragma unroll
        for (int r = 0; r < 4; ++r) {
            float sum = 0.0f;
            #pragma unroll
            for (int j = 0; j < 4; ++j) {
                int colg = nTile + wn * 64 + j * 16 + l16;
                float x = acc[i][j][r] + cbuf[bIdx * HID + colg];
                sum += fast_tanh(x) * vw[colg];
            }
            sum += __shfl_xor(sum, 1);
            sum += __shfl_xor(sum, 2);
            sum += __shfl_xor(sum, 4);
            sum += __shfl_xor(sum, 8);
            if (l16 == 0) {
                int rowl = wm * 64 + i * 16 + q * 4 + r;
                atomicAdd(&scores[sRow + rowl], sum);
            }
        }
    }
}

// ---------- kernel 3: softmax over S per batch, in place ----------
__global__ void k_softmax(float* __restrict__ sw) {
    int b = blockIdx.x;
    float* s = sw + (size_t)b * SEQ;
    int t = threadIdx.x;  // 256
    __shared__ float red[4];

    float lmax = -1e30f;
    for (int i = t; i < SEQ; i += 256) lmax = fmaxf(lmax, s[i]);
    for (int m = 1; m < 64; m <<= 1) lmax = fmaxf(lmax, __shfl_xor(lmax, m));
    if ((t & 63) == 0) red[t >> 6] = lmax;
    __syncthreads();
    float gmax = fmaxf(fmaxf(red[0], red[1]), fmaxf(red[2], red[3]));
    __syncthreads();

    float lsum = 0.0f;
    for (int i = t; i < SEQ; i += 256) lsum += __expf(s[i] - gmax);
    for (int m = 1; m < 64; m <<= 1) lsum += __shfl_xor(lsum, m);
    if ((t & 63) == 0) red[t >> 6] = lsum;
    __syncthreads();
    float inv = 1.0f / (red[0] + red[1] + red[2] + red[3]);

    for (int i = t; i < SEQ; i += 256) s[i] = __expf(s[i] - gmax) * inv;
}

// ---------- kernel 4: context[b][h] = sum_s w[b][s] * enc[b][s][h] ----------
// grid (16, 64): 16 s-chunks of 128 per batch; 256 threads, float2 per thread.
__global__ void k_context(const float* __restrict__ enc, const float* __restrict__ wts,
                          float* __restrict__ out) {
    int b  = blockIdx.y;
    int sc = blockIdx.x;
    int t  = threadIdx.x;
    const float* e = enc + ((size_t)b * SEQ + sc * 128) * HID + t * 2;
    const float* w = wts + (size_t)b * SEQ + sc * 128;
    float ax = 0.0f, ay = 0.0f;
    #pragma unroll 4
    for (int s = 0; s < 128; ++s) {
        float ws = w[s];
        float2 v = *(const float2*)(e + (size_t)s * HID);
        ax += ws * v.x;
        ay += ws * v.y;
    }
    atomicAdd(&out[b * HID + t * 2], ax);
    atomicAdd(&out[b * HID + t * 2 + 1], ay);
}

extern "C" void kernel_launch(void* const* d_in, const int* in_sizes, int n_in,
                              void* d_out, int out_size, void* d_ws, size_t ws_size,
                              hipStream_t stream) {
    const float* enc  = (const float*)d_in[0];  // [64][2048][512]
    const float* fin  = (const float*)d_in[1];  // [64][512]
    const float* attw = (const float*)d_in[2];  // [512][1024]
    const float* attb = (const float*)d_in[3];  // [512]
    const float* vw   = (const float*)d_in[4];  // [1][512]
    float* out = (float*)d_out;                 // [64][512]

    float* cbuf   = (float*)d_ws;               // 32768 floats
    float* scores = cbuf + BATCH * HID;         // 131072 floats (scores -> weights in place)

    hipMemsetAsync(scores, 0, (size_t)ROWS * sizeof(float), stream);
    hipMemsetAsync(out, 0, (size_t)BATCH * HID * sizeof(float), stream);

    k_fin<<<dim3(16, 64), 256, 0, stream>>>(fin, attw, attb, cbuf);
    k_energy<<<dim3(4, ROWS / 128), 256, 0, stream>>>(enc, attw, cbuf, vw, scores);
    k_softmax<<<BATCH, 256, 0, stream>>>(scores);
    k_context<<<dim3(16, 64), 256, 0, stream>>>(enc, scores, out);
}

// Round 2
// 566.183 us; speedup vs baseline: 1.0193x; 1.0193x over previous
//
#include <hip/hip_runtime.h>
#include <hip/hip_bf16.h>

// Problem constants (B=64, S=2048, H=512)
#define BATCH 64
#define SEQ   2048
#define HID   512
#define ROWS  (BATCH * SEQ)   // 131072

typedef __attribute__((ext_vector_type(8))) short short8;
typedef __attribute__((ext_vector_type(4))) float f32x4;

#define GLOBAL_AS __attribute__((address_space(1)))
#define LDS_AS    __attribute__((address_space(3)))

// async 16B global -> LDS (wave-uniform LDS base + lane*16)
__device__ __forceinline__ void g2l16(const void* g, void* l) {
    __builtin_amdgcn_global_load_lds((const GLOBAL_AS unsigned int*)g,
                                     (LDS_AS unsigned int*)l, 16, 0, 0);
}

// ---------- helpers ----------
__device__ inline unsigned int cvt2_bf16(float x, float y) {
    __hip_bfloat162 h = __float22bfloat162_rn(make_float2(x, y));
    union { __hip_bfloat162 h2; unsigned int u; } u;
    u.h2 = h;
    return u.u;  // low 16 = x, high 16 = y
}

__device__ inline float fast_tanh(float x) {
    float e = __expf(2.0f * x);
    return 1.0f - 2.0f / (e + 1.0f);
}

__device__ inline float bf16lo(unsigned int u) { return __uint_as_float(u << 16); }
__device__ inline float bf16hi(unsigned int u) { return __uint_as_float(u & 0xffff0000u); }

// ---------- conversion kernels ----------
// enc fp32 -> bf16, 8 elems/thread. grid 32768 x 256.
__global__ void k_cvt_enc(const float* __restrict__ in, unsigned short* __restrict__ out) {
    size_t i = ((size_t)blockIdx.x * 256 + threadIdx.x) * 8;
    float4 a0 = *(const float4*)(in + i);
    float4 a1 = *(const float4*)(in + i + 4);
    uint4 p;
    p.x = cvt2_bf16(a0.x, a0.y);
    p.y = cvt2_bf16(a0.z, a0.w);
    p.z = cvt2_bf16(a1.x, a1.y);
    p.w = cvt2_bf16(a1.z, a1.w);
    *(uint4*)(out + i) = p;
}

// w_enc = attw[:, :H] fp32 (strided) -> dense bf16 [512][512]. grid 512 x 256.
__global__ void k_cvt_w(const float* __restrict__ attw, unsigned short* __restrict__ wb) {
    int k = blockIdx.x;
    int t = threadIdx.x;
    float2 v = *(const float2*)(attw + (size_t)k * (2 * HID) + t * 2);
    *(unsigned int*)(wb + (size_t)k * HID + t * 2) = cvt2_bf16(v.x, v.y);
}

// ---------- kernel 1: c[b][k] = attn_b[k] + sum_h fin[b][h] * attn_w[k][H+h] ----------
__global__ void k_fin(const float* __restrict__ fin, const float* __restrict__ attw,
                      const float* __restrict__ attb, float* __restrict__ cbuf) {
    int b  = blockIdx.y;
    int k  = blockIdx.x * 32 + (threadIdx.x >> 3);
    int l8 = threadIdx.x & 7;
    const float* f = fin + b * HID;
    const float* w = attw + (size_t)k * (2 * HID) + HID;
    float s = 0.0f;
    for (int h = l8 * 4; h < HID; h += 32) {
        float4 a  = *(const float4*)(f + h);
        float4 ww = *(const float4*)(w + h);
        s += a.x * ww.x + a.y * ww.y + a.z * ww.z + a.w * ww.w;
    }
    s += __shfl_xor(s, 1);
    s += __shfl_xor(s, 2);
    s += __shfl_xor(s, 4);
    if (l8 == 0) cbuf[b * HID + k] = s + attb[k];
}

// ---------- kernel 2 (v2): bf16 inputs, global_load_lds staging, XOR-swizzled LDS ----------
// LDS layout: [row][pos] with 8 chunks of 16B per row; pos p of row r holds
// global k-chunk (p ^ (r&7)) -> breaks the 16-way bank aliasing of row-stride-128B.
__global__ __launch_bounds__(256) void k_energy2(
        const unsigned short* __restrict__ encb, const unsigned short* __restrict__ wb,
        const float* __restrict__ cbuf, const float* __restrict__ vw,
        float* __restrict__ scores) {
    __shared__ __align__(16) unsigned short As[128 * 64];
    __shared__ __align__(16) unsigned short Bs[128 * 64];

    const int nTile = blockIdx.x * 128;
    const int sRow  = blockIdx.y * 128;
    const int bIdx  = sRow >> 11;

    const int t    = threadIdx.x;
    const int lane = t & 63;
    const int wave = t >> 6;
    const int wm   = wave >> 1;
    const int wn   = wave & 1;
    const int l16  = lane & 15;
    const int q    = lane >> 4;

    const int lr = lane >> 3;          // 0..7
    const int lc = lane & 7;           // 0..7
    const int sw = lc ^ lr;            // swizzled chunk this lane fetches

    // per-lane global bases (elements)
    const unsigned short* gA = encb + (size_t)(sRow + wave * 32 + lr) * HID + sw * 8;
    const unsigned short* gB = wb   + (size_t)(nTile + wave * 32 + lr) * HID + sw * 8;

    f32x4 acc[4][4];
    #pragma unroll
    for (int i = 0; i < 4; ++i)
        #pragma unroll
        for (int j = 0; j < 4; ++j)
            acc[i][j] = (f32x4){0.f, 0.f, 0.f, 0.f};

    for (int h0 = 0; h0 < HID; h0 += 64) {
        #pragma unroll
        for (int j = 0; j < 4; ++j) {
            g2l16(gA + (size_t)(j * 8) * HID + h0, As + (wave * 32 + j * 8) * 64);
            g2l16(gB + (size_t)(j * 8) * HID + h0, Bs + (wave * 32 + j * 8) * 64);
        }
        __syncthreads();   // compiler drains vmcnt(0) here

        #pragma unroll
        for (int kk = 0; kk < 64; kk += 32) {
            short8 af[4], bf[4];
            #pragma unroll
            for (int i = 0; i < 4; ++i) {
                int row = wm * 64 + i * 16 + l16;
                int c   = (kk >> 3) + q;
                af[i] = *(const short8*)(&As[row * 64 + (c ^ (row & 7)) * 8]);
            }
            #pragma unroll
            for (int j = 0; j < 4; ++j) {
                int row = wn * 64 + j * 16 + l16;
                int c   = (kk >> 3) + q;
                bf[j] = *(const short8*)(&Bs[row * 64 + (c ^ (row & 7)) * 8]);
            }
            #pragma unroll
            for (int i = 0; i < 4; ++i)
                #pragma unroll
                for (int j = 0; j < 4; ++j)
                    acc[i][j] = __builtin_amdgcn_mfma_f32_16x16x32_bf16(
                        af[i], bf[j], acc[i][j], 0, 0, 0);
        }
        __syncthreads();
    }

    // epilogue: tanh, dot with v, 16-lane reduce, atomic partial scores
    // C/D mapping: col = lane&15, row = q*4 + reg
    #pragma unroll
    for (int i = 0; i < 4; ++i) {
        #pragma unroll
        for (int r = 0; r < 4; ++r) {
            float sum = 0.0f;
            #pragma unroll
            for (int j = 0; j < 4; ++j) {
                int colg = nTile + wn * 64 + j * 16 + l16;
                float x = acc[i][j][r] + cbuf[bIdx * HID + colg];
                sum += fast_tanh(x) * vw[colg];
            }
            sum += __shfl_xor(sum, 1);
            sum += __shfl_xor(sum, 2);
            sum += __shfl_xor(sum, 4);
            sum += __shfl_xor(sum, 8);
            if (l16 == 0) {
                int rowl = wm * 64 + i * 16 + q * 4 + r;
                atomicAdd(&scores[sRow + rowl], sum);
            }
        }
    }
}

// ---------- kernel 3: softmax over S per batch, in place ----------
__global__ void k_softmax(float* __restrict__ sw) {
    int b = blockIdx.x;
    float* s = sw + (size_t)b * SEQ;
    int t = threadIdx.x;  // 256
    __shared__ float red[4];

    float lmax = -1e30f;
    for (int i = t; i < SEQ; i += 256) lmax = fmaxf(lmax, s[i]);
    for (int m = 1; m < 64; m <<= 1) lmax = fmaxf(lmax, __shfl_xor(lmax, m));
    if ((t & 63) == 0) red[t >> 6] = lmax;
    __syncthreads();
    float gmax = fmaxf(fmaxf(red[0], red[1]), fmaxf(red[2], red[3]));
    __syncthreads();

    float lsum = 0.0f;
    for (int i = t; i < SEQ; i += 256) lsum += __expf(s[i] - gmax);
    for (int m = 1; m < 64; m <<= 1) lsum += __shfl_xor(lsum, m);
    if ((t & 63) == 0) red[t >> 6] = lsum;
    __syncthreads();
    float inv = 1.0f / (red[0] + red[1] + red[2] + red[3]);

    for (int i = t; i < SEQ; i += 256) s[i] = __expf(s[i] - gmax) * inv;
}

// ---------- kernel 4 (v2): context from bf16 enc ----------
// grid (32, 64): 32 s-chunks of 64 rows. 256 thr = 2 row-groups x 128 thr (4 cols each).
__global__ void k_context2(const unsigned short* __restrict__ encb,
                           const float* __restrict__ wts, float* __restrict__ out) {
    int b  = blockIdx.y;
    int sc = blockIdx.x;
    int t  = threadIdx.x;
    int g  = t >> 7;                 // 0..1
    int h  = (t & 127) * 4;
    const unsigned short* e = encb + ((size_t)b * SEQ + sc * 64 + g) * HID + h;
    const float* w = wts + (size_t)b * SEQ + sc * 64 + g;
    float4 acc = {0.f, 0.f, 0.f, 0.f};
    #pragma unroll 8
    for (int s = 0; s < 64; s += 2) {
        float ws = w[s];
        uint2 v = *(const uint2*)(e + (size_t)s * HID);
        acc.x += ws * bf16lo(v.x);
        acc.y += ws * bf16hi(v.x);
        acc.z += ws * bf16lo(v.y);
        acc.w += ws * bf16hi(v.y);
    }
    float* o = out + b * HID + h;
    atomicAdd(o + 0, acc.x);
    atomicAdd(o + 1, acc.y);
    atomicAdd(o + 2, acc.z);
    atomicAdd(o + 3, acc.w);
}

// ================= fallback path (round-1, in-kernel cvt) =================
#define BK  64
#define LDA 72

__global__ __launch_bounds__(256) void k_energy_fb(
        const float* __restrict__ enc, const float* __restrict__ attw,
        const float* __restrict__ cbuf, const float* __restrict__ vw,
        float* __restrict__ scores) {
    __shared__ __align__(16) unsigned short As[128 * LDA];
    __shared__ __align__(16) unsigned short Bs[128 * LDA];

    const int nTile = blockIdx.x * 128;
    const int sRow  = blockIdx.y * 128;
    const int bIdx  = sRow >> 11;
    const int t = threadIdx.x, lane = t & 63, wave = t >> 6;
    const int wm = wave >> 1, wn = wave & 1, l16 = lane & 15, q = lane >> 4;
    const int tr = t >> 3, tc = (t & 7) * 8;

    f32x4 acc[4][4];
    #pragma unroll
    for (int i = 0; i < 4; ++i)
        #pragma unroll
        for (int j = 0; j < 4; ++j) acc[i][j] = (f32x4){0.f, 0.f, 0.f, 0.f};

    for (int h0 = 0; h0 < HID; h0 += BK) {
        #pragma unroll
        for (int i = 0; i < 4; ++i) {
            int row = tr + i * 32;
            const float* gA = enc + (size_t)(sRow + row) * HID + h0 + tc;
            float4 a0 = *(const float4*)gA;
            float4 a1 = *(const float4*)(gA + 4);
            uint4 pa = {cvt2_bf16(a0.x, a0.y), cvt2_bf16(a0.z, a0.w),
                        cvt2_bf16(a1.x, a1.y), cvt2_bf16(a1.z, a1.w)};
            *(uint4*)(&As[row * LDA + tc]) = pa;
            const float* gB = attw + (size_t)(nTile + row) * (2 * HID) + h0 + tc;
            float4 b0 = *(const float4*)gB;
            float4 b1 = *(const float4*)(gB + 4);
            uint4 pb = {cvt2_bf16(b0.x, b0.y), cvt2_bf16(b0.z, b0.w),
                        cvt2_bf16(b1.x, b1.y), cvt2_bf16(b1.z, b1.w)};
            *(uint4*)(&Bs[row * LDA + tc]) = pb;
        }
        __syncthreads();
        #pragma unroll
        for (int kk = 0; kk < BK; kk += 32) {
            short8 af[4], bf[4];
            #pragma unroll
            for (int i = 0; i < 4; ++i)
                af[i] = *(const short8*)(&As[(wm * 64 + i * 16 + l16) * LDA + kk + q * 8]);
            #pragma unroll
            for (int j = 0; j < 4; ++j)
                bf[j] = *(const short8*)(&Bs[(wn * 64 + j * 16 + l16) * LDA + kk + q * 8]);
            #pragma unroll
            for (int i = 0; i < 4; ++i)
                #pragma unroll
                for (int j = 0; j < 4; ++j)
                    acc[i][j] = __builtin_amdgcn_mfma_f32_16x16x32_bf16(
                        af[i], bf[j], acc[i][j], 0, 0, 0);
        }
        __syncthreads();
    }
    #pragma unroll
    for (int i = 0; i < 4; ++i) {
        #pragma unroll
        for (int r = 0; r < 4; ++r) {
            float sum = 0.0f;
            #pragma unroll
            for (int j = 0; j < 4; ++j) {
                int colg = nTile + wn * 64 + j * 16 + l16;
                float x = acc[i][j][r] + cbuf[bIdx * HID + colg];
                sum += fast_tanh(x) * vw[colg];
            }
            sum += __shfl_xor(sum, 1);
            sum += __shfl_xor(sum, 2);
            sum += __shfl_xor(sum, 4);
            sum += __shfl_xor(sum, 8);
            if (l16 == 0) atomicAdd(&scores[sRow + wm * 64 + i * 16 + q * 4 + r], sum);
        }
    }
}

__global__ void k_context_fb(const float* __restrict__ enc, const float* __restrict__ wts,
                             float* __restrict__ out) {
    int b = blockIdx.y, sc = blockIdx.x, t = threadIdx.x;
    const float* e = enc + ((size_t)b * SEQ + sc * 128) * HID + t * 2;
    const float* w = wts + (size_t)b * SEQ + sc * 128;
    float ax = 0.f, ay = 0.f;
    #pragma unroll 4
    for (int s = 0; s < 128; ++s) {
        float ws = w[s];
        float2 v = *(const float2*)(e + (size_t)s * HID);
        ax += ws * v.x;
        ay += ws * v.y;
    }
    atomicAdd(&out[b * HID + t * 2], ax);
    atomicAdd(&out[b * HID + t * 2 + 1], ay);
}

extern "C" void kernel_launch(void* const* d_in, const int* in_sizes, int n_in,
                              void* d_out, int out_size, void* d_ws, size_t ws_size,
                              hipStream_t stream) {
    const float* enc  = (const float*)d_in[0];
    const float* fin  = (const float*)d_in[1];
    const float* attw = (const float*)d_in[2];
    const float* attb = (const float*)d_in[3];
    const float* vw   = (const float*)d_in[4];
    float* out = (float*)d_out;

    char* ws = (char*)d_ws;
    float* cbuf   = (float*)ws;                            // 131072 B
    float* scores = (float*)(ws + 131072);                 // 524288 B
    unsigned short* wb   = (unsigned short*)(ws + 131072 + 524288);            // 524288 B
    unsigned short* encb = (unsigned short*)(ws + 131072 + 524288 + 524288);   // 134217728 B
    const size_t need = 131072ull + 524288 + 524288 + 134217728;

    hipMemsetAsync(scores, 0, (size_t)ROWS * sizeof(float), stream);
    hipMemsetAsync(out, 0, (size_t)BATCH * HID * sizeof(float), stream);

    k_fin<<<dim3(16, 64), 256, 0, stream>>>(fin, attw, attb, cbuf);

    if (ws_size >= need) {
        k_cvt_enc<<<32768, 256, 0, stream>>>(enc, encb);
        k_cvt_w<<<512, 256, 0, stream>>>(attw, wb);
        k_energy2<<<dim3(4, ROWS / 128), 256, 0, stream>>>(encb, wb, cbuf, vw, scores);
        k_softmax<<<BATCH, 256, 0, stream>>>(scores);
        k_context2<<<dim3(32, 64), 256, 0, stream>>>(encb, scores, out);
    } else {
        k_energy_fb<<<dim3(4, ROWS / 128), 256, 0, stream>>>(enc, attw, cbuf, vw, scores);
        k_softmax<<<BATCH, 256, 0, stream>>>(scores);
        k_context_fb<<<dim3(16, 64), 256, 0, stream>>>(enc, scores, out);
    }
}

// Round 3
// 540.835 us; speedup vs baseline: 1.0670x; 1.0469x over previous
//
#include <hip/hip_runtime.h>
#include <hip/hip_bf16.h>

// Problem constants (B=64, S=2048, H=512)
#define BATCH 64
#define SEQ   2048
#define HID   512
#define ROWS  (BATCH * SEQ)   // 131072

typedef __attribute__((ext_vector_type(8))) short short8;
typedef __attribute__((ext_vector_type(4))) float f32x4;

#define GLOBAL_AS __attribute__((address_space(1)))
#define LDS_AS    __attribute__((address_space(3)))

__device__ __forceinline__ void g2l16(const void* g, void* l) {
    __builtin_amdgcn_global_load_lds((const GLOBAL_AS unsigned int*)g,
                                     (LDS_AS unsigned int*)l, 16, 0, 0);
}

__device__ inline unsigned int cvt2_bf16(float x, float y) {
    __hip_bfloat162 h = __float22bfloat162_rn(make_float2(x, y));
    union { __hip_bfloat162 h2; unsigned int u; } u;
    u.h2 = h;
    return u.u;
}

__device__ inline float fast_tanh(float x) {
    float e = __expf(2.0f * x);
    return 1.0f - 2.0f / (e + 1.0f);
}

__device__ inline float bf16lo(unsigned int u) { return __uint_as_float(u << 16); }
__device__ inline float bf16hi(unsigned int u) { return __uint_as_float(u & 0xffff0000u); }

// ---------- k_prep: fused cvt_enc + cvt_w + fin (one dispatch) ----------
// blocks [0, 32768)        : enc fp32 -> bf16, 2048 elems/block
// blocks [32768, 32896)    : w_enc fp32 (strided) -> dense bf16 [512][512]
// blocks [32896, 33920)    : c[b][k] = attb[k] + fin[b]·attw[k][H:]
#define PREP_GRID 33920
__global__ void k_prep(const float* __restrict__ enc, const float* __restrict__ attw,
                       const float* __restrict__ attb, const float* __restrict__ fin,
                       unsigned short* __restrict__ encb, unsigned short* __restrict__ wb,
                       float* __restrict__ cbuf) {
    int bid = blockIdx.x;
    int t   = threadIdx.x;
    if (bid < 32768) {
        size_t i = ((size_t)bid * 256 + t) * 8;
        float4 a0 = *(const float4*)(enc + i);
        float4 a1 = *(const float4*)(enc + i + 4);
        uint4 p = {cvt2_bf16(a0.x, a0.y), cvt2_bf16(a0.z, a0.w),
                   cvt2_bf16(a1.x, a1.y), cvt2_bf16(a1.z, a1.w)};
        *(uint4*)(encb + i) = p;
    } else if (bid < 32896) {
        size_t e = ((size_t)(bid - 32768) * 256 + t) * 8;   // [0, 262144)
        int k = (int)(e >> 9);
        int h = (int)(e & 511);
        const float* g = attw + (size_t)k * (2 * HID) + h;
        float4 a0 = *(const float4*)g;
        float4 a1 = *(const float4*)(g + 4);
        uint4 p = {cvt2_bf16(a0.x, a0.y), cvt2_bf16(a0.z, a0.w),
                   cvt2_bf16(a1.x, a1.y), cvt2_bf16(a1.z, a1.w)};
        *(uint4*)(wb + (size_t)k * HID + h) = p;
    } else {
        int fb = bid - 32896;                 // [0, 1024)
        int b  = fb >> 4;
        int k  = (fb & 15) * 32 + (t >> 3);
        int l8 = t & 7;
        const float* f = fin + b * HID;
        const float* w = attw + (size_t)k * (2 * HID) + HID;
        float s = 0.0f;
        for (int h = l8 * 4; h < HID; h += 32) {
            float4 a  = *(const float4*)(f + h);
            float4 ww = *(const float4*)(w + h);
            s += a.x * ww.x + a.y * ww.y + a.z * ww.z + a.w * ww.w;
        }
        s += __shfl_xor(s, 1);
        s += __shfl_xor(s, 2);
        s += __shfl_xor(s, 4);
        if (l8 == 0) cbuf[b * HID + k] = s + attb[k];
    }
}

// ---------- k_energy3: bf16 MFMA GEMM + tanh + v-dot -> per-nTile partial scores ----------
// No global atomics: block-local LDS reduce, plain store to sp[nTileIdx][row].
__global__ __launch_bounds__(256) void k_energy3(
        const unsigned short* __restrict__ encb, const unsigned short* __restrict__ wb,
        const float* __restrict__ cbuf, const float* __restrict__ vw,
        float* __restrict__ sp) {
    __shared__ __align__(16) unsigned short As[128 * 64];
    __shared__ __align__(16) unsigned short Bs[128 * 64];
    __shared__ float ssc[128];

    const int nTile = blockIdx.x * 128;
    const int sRow  = blockIdx.y * 128;
    const int bIdx  = sRow >> 11;

    const int t    = threadIdx.x;
    const int lane = t & 63;
    const int wave = t >> 6;
    const int wm   = wave >> 1;
    const int wn   = wave & 1;
    const int l16  = lane & 15;
    const int q    = lane >> 4;

    const int lr = lane >> 3;          // 0..7
    const int lc = lane & 7;           // 0..7
    const int sw = lc ^ lr;            // swizzled 16B chunk this lane fetches

    const unsigned short* gA = encb + (size_t)(sRow + wave * 32 + lr) * HID + sw * 8;
    const unsigned short* gB = wb   + (size_t)(nTile + wave * 32 + lr) * HID + sw * 8;

    f32x4 acc[4][4];
    #pragma unroll
    for (int i = 0; i < 4; ++i)
        #pragma unroll
        for (int j = 0; j < 4; ++j)
            acc[i][j] = (f32x4){0.f, 0.f, 0.f, 0.f};

    for (int h0 = 0; h0 < HID; h0 += 64) {
        #pragma unroll
        for (int j = 0; j < 4; ++j) {
            g2l16(gA + (size_t)(j * 8) * HID + h0, As + (wave * 32 + j * 8) * 64);
            g2l16(gB + (size_t)(j * 8) * HID + h0, Bs + (wave * 32 + j * 8) * 64);
        }
        __syncthreads();

        #pragma unroll
        for (int kk = 0; kk < 64; kk += 32) {
            short8 af[4], bf[4];
            #pragma unroll
            for (int i = 0; i < 4; ++i) {
                int row = wm * 64 + i * 16 + l16;
                int c   = (kk >> 3) + q;
                af[i] = *(const short8*)(&As[row * 64 + (c ^ (row & 7)) * 8]);
            }
            #pragma unroll
            for (int j = 0; j < 4; ++j) {
                int row = wn * 64 + j * 16 + l16;
                int c   = (kk >> 3) + q;
                bf[j] = *(const short8*)(&Bs[row * 64 + (c ^ (row & 7)) * 8]);
            }
            #pragma unroll
            for (int i = 0; i < 4; ++i)
                #pragma unroll
                for (int j = 0; j < 4; ++j)
                    acc[i][j] = __builtin_amdgcn_mfma_f32_16x16x32_bf16(
                        af[i], bf[j], acc[i][j], 0, 0, 0);
        }
        __syncthreads();
    }

    if (t < 128) ssc[t] = 0.0f;
    __syncthreads();

    // hoist per-column constants (depend on j,l16,wn only)
    float cv[4], vv[4];
    #pragma unroll
    for (int j = 0; j < 4; ++j) {
        int colg = nTile + wn * 64 + j * 16 + l16;
        cv[j] = cbuf[bIdx * HID + colg];
        vv[j] = vw[colg];
    }

    // C/D mapping: col = lane&15, row = q*4 + reg
    #pragma unroll
    for (int i = 0; i < 4; ++i) {
        #pragma unroll
        for (int r = 0; r < 4; ++r) {
            float sum = 0.0f;
            #pragma unroll
            for (int j = 0; j < 4; ++j)
                sum += fast_tanh(acc[i][j][r] + cv[j]) * vv[j];
            sum += __shfl_xor(sum, 1);
            sum += __shfl_xor(sum, 2);
            sum += __shfl_xor(sum, 4);
            sum += __shfl_xor(sum, 8);
            if (l16 == 0)
                atomicAdd(&ssc[wm * 64 + i * 16 + q * 4 + r], sum);  // LDS atomic, 2-way
        }
    }
    __syncthreads();
    if (t < 128) sp[(size_t)blockIdx.x * ROWS + sRow + t] = ssc[t];
}

// ---------- k_softmax4: sum 4 partials, softmax over S per batch -> wts ----------
__global__ void k_softmax4(const float* __restrict__ sp, float* __restrict__ wts) {
    int b = blockIdx.x;
    int t = threadIdx.x;  // 256
    const float* p = sp + (size_t)b * SEQ;
    float* w = wts + (size_t)b * SEQ;
    __shared__ float red[4];

    float lmax = -1e30f;
    for (int i = t; i < SEQ; i += 256) {
        float v = p[i] + p[i + ROWS] + p[i + 2 * ROWS] + p[i + 3 * ROWS];
        w[i] = v;
        lmax = fmaxf(lmax, v);
    }
    for (int m = 1; m < 64; m <<= 1) lmax = fmaxf(lmax, __shfl_xor(lmax, m));
    if ((t & 63) == 0) red[t >> 6] = lmax;
    __syncthreads();
    float gmax = fmaxf(fmaxf(red[0], red[1]), fmaxf(red[2], red[3]));
    __syncthreads();

    float lsum = 0.0f;
    for (int i = t; i < SEQ; i += 256) lsum += __expf(w[i] - gmax);
    for (int m = 1; m < 64; m <<= 1) lsum += __shfl_xor(lsum, m);
    if ((t & 63) == 0) red[t >> 6] = lsum;
    __syncthreads();
    float inv = 1.0f / (red[0] + red[1] + red[2] + red[3]);

    for (int i = t; i < SEQ; i += 256) w[i] = __expf(w[i] - gmax) * inv;
}

// ---------- k_context3: context[b][h] = sum_s w[b][s] * enc[b][s][h] ----------
// grid (8, 64): 8 s-chunks of 256 rows; thread t owns cols 2t, 2t+1; weights in LDS.
__global__ void k_context3(const unsigned short* __restrict__ encb,
                           const float* __restrict__ wts, float* __restrict__ out) {
    int b  = blockIdx.y;
    int sc = blockIdx.x;
    int t  = threadIdx.x;
    __shared__ float w[256];
    w[t] = wts[(size_t)b * SEQ + sc * 256 + t];
    __syncthreads();
    const unsigned short* e = encb + ((size_t)b * SEQ + sc * 256) * HID + t * 2;
    float ax = 0.0f, ay = 0.0f;
    #pragma unroll 8
    for (int s = 0; s < 256; ++s) {
        float ws = w[s];
        unsigned int v = *(const unsigned int*)(e + (size_t)s * HID);
        ax += ws * bf16lo(v);
        ay += ws * bf16hi(v);
    }
    atomicAdd(&out[b * HID + t * 2], ax);       // 8-way contention
    atomicAdd(&out[b * HID + t * 2 + 1], ay);
}

// ================= fallback path (fp32 in-kernel cvt, small ws) =================
#define BK  64
#define LDA 72

__global__ __launch_bounds__(256) void k_energy_fb(
        const float* __restrict__ enc, const float* __restrict__ attw,
        const float* __restrict__ cbuf, const float* __restrict__ vw,
        float* __restrict__ scores) {
    __shared__ __align__(16) unsigned short As[128 * LDA];
    __shared__ __align__(16) unsigned short Bs[128 * LDA];
    const int nTile = blockIdx.x * 128;
    const int sRow  = blockIdx.y * 128;
    const int bIdx  = sRow >> 11;
    const int t = threadIdx.x, lane = t & 63, wave = t >> 6;
    const int wm = wave >> 1, wn = wave & 1, l16 = lane & 15, q = lane >> 4;
    const int tr = t >> 3, tc = (t & 7) * 8;

    f32x4 acc[4][4];
    #pragma unroll
    for (int i = 0; i < 4; ++i)
        #pragma unroll
        for (int j = 0; j < 4; ++j) acc[i][j] = (f32x4){0.f, 0.f, 0.f, 0.f};

    for (int h0 = 0; h0 < HID; h0 += BK) {
        #pragma unroll
        for (int i = 0; i < 4; ++i) {
            int row = tr + i * 32;
            const float* gA = enc + (size_t)(sRow + row) * HID + h0 + tc;
            float4 a0 = *(const float4*)gA;
            float4 a1 = *(const float4*)(gA + 4);
            uint4 pa = {cvt2_bf16(a0.x, a0.y), cvt2_bf16(a0.z, a0.w),
                        cvt2_bf16(a1.x, a1.y), cvt2_bf16(a1.z, a1.w)};
            *(uint4*)(&As[row * LDA + tc]) = pa;
            const float* gB = attw + (size_t)(nTile + row) * (2 * HID) + h0 + tc;
            float4 b0 = *(const float4*)gB;
            float4 b1 = *(const float4*)(gB + 4);
            uint4 pb = {cvt2_bf16(b0.x, b0.y), cvt2_bf16(b0.z, b0.w),
                        cvt2_bf16(b1.x, b1.y), cvt2_bf16(b1.z, b1.w)};
            *(uint4*)(&Bs[row * LDA + tc]) = pb;
        }
        __syncthreads();
        #pragma unroll
        for (int kk = 0; kk < BK; kk += 32) {
            short8 af[4], bf[4];
            #pragma unroll
            for (int i = 0; i < 4; ++i)
                af[i] = *(const short8*)(&As[(wm * 64 + i * 16 + l16) * LDA + kk + q * 8]);
            #pragma unroll
            for (int j = 0; j < 4; ++j)
                bf[j] = *(const short8*)(&Bs[(wn * 64 + j * 16 + l16) * LDA + kk + q * 8]);
            #pragma unroll
            for (int i = 0; i < 4; ++i)
                #pragma unroll
                for (int j = 0; j < 4; ++j)
                    acc[i][j] = __builtin_amdgcn_mfma_f32_16x16x32_bf16(
                        af[i], bf[j], acc[i][j], 0, 0, 0);
        }
        __syncthreads();
    }
    #pragma unroll
    for (int i = 0; i < 4; ++i) {
        #pragma unroll
        for (int r = 0; r < 4; ++r) {
            float sum = 0.0f;
            #pragma unroll
            for (int j = 0; j < 4; ++j) {
                int colg = nTile + wn * 64 + j * 16 + l16;
                sum += fast_tanh(acc[i][j][r] + cbuf[bIdx * HID + colg]) * vw[colg];
            }
            sum += __shfl_xor(sum, 1);
            sum += __shfl_xor(sum, 2);
            sum += __shfl_xor(sum, 4);
            sum += __shfl_xor(sum, 8);
            if (l16 == 0) atomicAdd(&scores[sRow + wm * 64 + i * 16 + q * 4 + r], sum);
        }
    }
}

__global__ void k_softmax(float* __restrict__ sw) {
    int b = blockIdx.x;
    float* s = sw + (size_t)b * SEQ;
    int t = threadIdx.x;
    __shared__ float red[4];
    float lmax = -1e30f;
    for (int i = t; i < SEQ; i += 256) lmax = fmaxf(lmax, s[i]);
    for (int m = 1; m < 64; m <<= 1) lmax = fmaxf(lmax, __shfl_xor(lmax, m));
    if ((t & 63) == 0) red[t >> 6] = lmax;
    __syncthreads();
    float gmax = fmaxf(fmaxf(red[0], red[1]), fmaxf(red[2], red[3]));
    __syncthreads();
    float lsum = 0.0f;
    for (int i = t; i < SEQ; i += 256) lsum += __expf(s[i] - gmax);
    for (int m = 1; m < 64; m <<= 1) lsum += __shfl_xor(lsum, m);
    if ((t & 63) == 0) red[t >> 6] = lsum;
    __syncthreads();
    float inv = 1.0f / (red[0] + red[1] + red[2] + red[3]);
    for (int i = t; i < SEQ; i += 256) s[i] = __expf(s[i] - gmax) * inv;
}

__global__ void k_fin_fb(const float* __restrict__ fin, const float* __restrict__ attw,
                         const float* __restrict__ attb, float* __restrict__ cbuf) {
    int b  = blockIdx.y;
    int k  = blockIdx.x * 32 + (threadIdx.x >> 3);
    int l8 = threadIdx.x & 7;
    const float* f = fin + b * HID;
    const float* w = attw + (size_t)k * (2 * HID) + HID;
    float s = 0.0f;
    for (int h = l8 * 4; h < HID; h += 32) {
        float4 a  = *(const float4*)(f + h);
        float4 ww = *(const float4*)(w + h);
        s += a.x * ww.x + a.y * ww.y + a.z * ww.z + a.w * ww.w;
    }
    s += __shfl_xor(s, 1);
    s += __shfl_xor(s, 2);
    s += __shfl_xor(s, 4);
    if (l8 == 0) cbuf[b * HID + k] = s + attb[k];
}

__global__ void k_context_fb(const float* __restrict__ enc, const float* __restrict__ wts,
                             float* __restrict__ out) {
    int b = blockIdx.y, sc = blockIdx.x, t = threadIdx.x;
    const float* e = enc + ((size_t)b * SEQ + sc * 128) * HID + t * 2;
    const float* w = wts + (size_t)b * SEQ + sc * 128;
    float ax = 0.f, ay = 0.f;
    #pragma unroll 4
    for (int s = 0; s < 128; ++s) {
        float ws = w[s];
        float2 v = *(const float2*)(e + (size_t)s * HID);
        ax += ws * v.x;
        ay += ws * v.y;
    }
    atomicAdd(&out[b * HID + t * 2], ax);
    atomicAdd(&out[b * HID + t * 2 + 1], ay);
}

extern "C" void kernel_launch(void* const* d_in, const int* in_sizes, int n_in,
                              void* d_out, int out_size, void* d_ws, size_t ws_size,
                              hipStream_t stream) {
    const float* enc  = (const float*)d_in[0];
    const float* fin  = (const float*)d_in[1];
    const float* attw = (const float*)d_in[2];
    const float* attb = (const float*)d_in[3];
    const float* vw   = (const float*)d_in[4];
    float* out = (float*)d_out;

    char* ws = (char*)d_ws;
    float* cbuf = (float*)ws;                                   // 131072 B
    float* sp   = (float*)(ws + 131072);                        // 4*524288 B partial scores
    float* wts  = (float*)(ws + 131072 + 4 * 524288);           // 524288 B
    unsigned short* wb   = (unsigned short*)(ws + 131072 + 5 * 524288);            // 524288 B
    unsigned short* encb = (unsigned short*)(ws + 131072 + 6 * 524288);            // 134217728 B
    const size_t need = 131072ull + 6 * 524288 + 134217728;

    hipMemsetAsync(out, 0, (size_t)BATCH * HID * sizeof(float), stream);

    if (ws_size >= need) {
        k_prep<<<PREP_GRID, 256, 0, stream>>>(enc, attw, attb, fin, encb, wb, cbuf);
        k_energy3<<<dim3(4, ROWS / 128), 256, 0, stream>>>(encb, wb, cbuf, vw, sp);
        k_softmax4<<<BATCH, 256, 0, stream>>>(sp, wts);
        k_context3<<<dim3(8, 64), 256, 0, stream>>>(encb, wts, out);
    } else {
        hipMemsetAsync(sp, 0, (size_t)ROWS * sizeof(float), stream);
        k_fin_fb<<<dim3(16, 64), 256, 0, stream>>>(fin, attw, attb, cbuf);
        k_energy_fb<<<dim3(4, ROWS / 128), 256, 0, stream>>>(enc, attw, cbuf, vw, sp);
        k_softmax<<<BATCH, 256, 0, stream>>>(sp);
        k_context_fb<<<dim3(16, 64), 256, 0, stream>>>(enc, sp, out);
    }
}

// Round 4
// 500.482 us; speedup vs baseline: 1.1531x; 1.0806x over previous
//
#include <hip/hip_runtime.h>
#include <hip/hip_bf16.h>

// Problem constants (B=64, S=2048, H=512)
#define BATCH 64
#define SEQ   2048
#define HID   512
#define ROWS  (BATCH * SEQ)   // 131072

typedef __attribute__((ext_vector_type(8))) short short8;
typedef __attribute__((ext_vector_type(4))) float f32x4;

#define GLOBAL_AS __attribute__((address_space(1)))
#define LDS_AS    __attribute__((address_space(3)))

__device__ __forceinline__ void g2l16(const void* g, void* l) {
    __builtin_amdgcn_global_load_lds((const GLOBAL_AS unsigned int*)g,
                                     (LDS_AS unsigned int*)l, 16, 0, 0);
}

__device__ inline unsigned int cvt2_bf16(float x, float y) {
    __hip_bfloat162 h = __float22bfloat162_rn(make_float2(x, y));
    union { __hip_bfloat162 h2; unsigned int u; } u;
    u.h2 = h;
    return u.u;
}

__device__ inline float fast_tanh(float x) {
    float e = __expf(2.0f * x);
    return 1.0f - 2.0f / (e + 1.0f);
}

__device__ inline float bf16lo(unsigned int u) { return __uint_as_float(u << 16); }
__device__ inline float bf16hi(unsigned int u) { return __uint_as_float(u & 0xffff0000u); }

// ---------- k_prep: fused cvt_enc + cvt_w + fin (one dispatch) ----------
#define PREP_GRID 33920
__global__ void k_prep(const float* __restrict__ enc, const float* __restrict__ attw,
                       const float* __restrict__ attb, const float* __restrict__ fin,
                       unsigned short* __restrict__ encb, unsigned short* __restrict__ wb,
                       float* __restrict__ cbuf) {
    int bid = blockIdx.x;
    int t   = threadIdx.x;
    if (bid < 32768) {
        size_t i = ((size_t)bid * 256 + t) * 8;
        float4 a0 = *(const float4*)(enc + i);
        float4 a1 = *(const float4*)(enc + i + 4);
        uint4 p = {cvt2_bf16(a0.x, a0.y), cvt2_bf16(a0.z, a0.w),
                   cvt2_bf16(a1.x, a1.y), cvt2_bf16(a1.z, a1.w)};
        *(uint4*)(encb + i) = p;
    } else if (bid < 32896) {
        size_t e = ((size_t)(bid - 32768) * 256 + t) * 8;   // [0, 262144)
        int k = (int)(e >> 9);
        int h = (int)(e & 511);
        const float* g = attw + (size_t)k * (2 * HID) + h;
        float4 a0 = *(const float4*)g;
        float4 a1 = *(const float4*)(g + 4);
        uint4 p = {cvt2_bf16(a0.x, a0.y), cvt2_bf16(a0.z, a0.w),
                   cvt2_bf16(a1.x, a1.y), cvt2_bf16(a1.z, a1.w)};
        *(uint4*)(wb + (size_t)k * HID + h) = p;
    } else {
        int fb = bid - 32896;                 // [0, 1024)
        int b  = fb >> 4;
        int k  = (fb & 15) * 32 + (t >> 3);
        int l8 = t & 7;
        const float* f = fin + b * HID;
        const float* w = attw + (size_t)k * (2 * HID) + HID;
        float s = 0.0f;
        for (int h = l8 * 4; h < HID; h += 32) {
            float4 a  = *(const float4*)(f + h);
            float4 ww = *(const float4*)(w + h);
            s += a.x * ww.x + a.y * ww.y + a.z * ww.z + a.w * ww.w;
        }
        s += __shfl_xor(s, 1);
        s += __shfl_xor(s, 2);
        s += __shfl_xor(s, 4);
        if (l8 == 0) cbuf[b * HID + k] = s + attb[k];
    }
}

// ---------- k_energy4: 2 n-tiles per block (256 cols), A staged once per slab ----------
// grid (2, 1024). Per slab per wave: 12 g2l16, 32 MFMAs (vs 8/16 before).
// Partial scores: sp[nHalf][row], 2 partials summed by k_context4.
__global__ __launch_bounds__(256, 2) void k_energy4(
        const unsigned short* __restrict__ encb, const unsigned short* __restrict__ wb,
        const float* __restrict__ cbuf, const float* __restrict__ vw,
        float* __restrict__ sp) {
    __shared__ __align__(16) unsigned short As[128 * 64];        // 16 KB
    __shared__ __align__(16) unsigned short Bs[2 * 128 * 64];    // 32 KB
    __shared__ float ssc[128];

    const int nBase = blockIdx.x * 256;     // 0 or 256
    const int sRow  = blockIdx.y * 128;
    const int bIdx  = sRow >> 11;

    const int t    = threadIdx.x;
    const int lane = t & 63;
    const int wave = t >> 6;
    const int wm   = wave >> 1;
    const int wn   = wave & 1;
    const int l16  = lane & 15;
    const int q    = lane >> 4;

    const int lr = lane >> 3;          // 0..7
    const int lc = lane & 7;           // 0..7
    const int sw = lc ^ lr;            // swizzled 16B chunk this lane fetches

    const unsigned short* gA  = encb + (size_t)(sRow + wave * 32 + lr) * HID + sw * 8;
    const unsigned short* gB0 = wb   + (size_t)(nBase + wave * 32 + lr) * HID + sw * 8;
    const unsigned short* gB1 = wb   + (size_t)(nBase + 128 + wave * 32 + lr) * HID + sw * 8;

    f32x4 acc0[4][4], acc1[4][4];
    #pragma unroll
    for (int i = 0; i < 4; ++i)
        #pragma unroll
        for (int j = 0; j < 4; ++j) {
            acc0[i][j] = (f32x4){0.f, 0.f, 0.f, 0.f};
            acc1[i][j] = (f32x4){0.f, 0.f, 0.f, 0.f};
        }

    for (int h0 = 0; h0 < HID; h0 += 64) {
        #pragma unroll
        for (int j = 0; j < 4; ++j) {
            g2l16(gA  + (size_t)(j * 8) * HID + h0, As + (wave * 32 + j * 8) * 64);
            g2l16(gB0 + (size_t)(j * 8) * HID + h0, Bs + (wave * 32 + j * 8) * 64);
            g2l16(gB1 + (size_t)(j * 8) * HID + h0, Bs + (128 + wave * 32 + j * 8) * 64);
        }
        __syncthreads();

        #pragma unroll
        for (int kk = 0; kk < 64; kk += 32) {
            short8 af[4], bf0[4], bf1[4];
            #pragma unroll
            for (int i = 0; i < 4; ++i) {
                int row = wm * 64 + i * 16 + l16;
                int c   = (kk >> 3) + q;
                af[i] = *(const short8*)(&As[row * 64 + (c ^ (row & 7)) * 8]);
            }
            #pragma unroll
            for (int j = 0; j < 4; ++j) {
                int row = wn * 64 + j * 16 + l16;
                int c   = (kk >> 3) + q;
                bf0[j] = *(const short8*)(&Bs[row * 64 + (c ^ (row & 7)) * 8]);
                bf1[j] = *(const short8*)(&Bs[(128 + row) * 64 + (c ^ (row & 7)) * 8]);
            }
            #pragma unroll
            for (int i = 0; i < 4; ++i)
                #pragma unroll
                for (int j = 0; j < 4; ++j) {
                    acc0[i][j] = __builtin_amdgcn_mfma_f32_16x16x32_bf16(
                        af[i], bf0[j], acc0[i][j], 0, 0, 0);
                    acc1[i][j] = __builtin_amdgcn_mfma_f32_16x16x32_bf16(
                        af[i], bf1[j], acc1[i][j], 0, 0, 0);
                }
        }
        __syncthreads();
    }

    if (t < 128) ssc[t] = 0.0f;
    __syncthreads();

    // per-column constants for both n-tiles
    float cv0[4], vv0[4], cv1[4], vv1[4];
    #pragma unroll
    for (int j = 0; j < 4; ++j) {
        int c0 = nBase + wn * 64 + j * 16 + l16;
        int c1 = c0 + 128;
        cv0[j] = cbuf[bIdx * HID + c0];
        vv0[j] = vw[c0];
        cv1[j] = cbuf[bIdx * HID + c1];
        vv1[j] = vw[c1];
    }

    // C/D mapping: col = lane&15, row = q*4 + reg
    #pragma unroll
    for (int i = 0; i < 4; ++i) {
        #pragma unroll
        for (int r = 0; r < 4; ++r) {
            float sum = 0.0f;
            #pragma unroll
            for (int j = 0; j < 4; ++j) {
                sum += fast_tanh(acc0[i][j][r] + cv0[j]) * vv0[j];
                sum += fast_tanh(acc1[i][j][r] + cv1[j]) * vv1[j];
            }
            sum += __shfl_xor(sum, 1);
            sum += __shfl_xor(sum, 2);
            sum += __shfl_xor(sum, 4);
            sum += __shfl_xor(sum, 8);
            if (l16 == 0)
                atomicAdd(&ssc[wm * 64 + i * 16 + q * 4 + r], sum);  // LDS atomic
        }
    }
    __syncthreads();
    if (t < 128) sp[(size_t)blockIdx.x * ROWS + sRow + t] = ssc[t];
}

// ---------- k_context4: fused softmax (from 2 partials) + weighted sum ----------
// grid (8, 64). Each block recomputes the batch's softmax stats (deterministic,
// identical across the 8 blocks of a batch), then streams its 256-row chunk.
__global__ void k_context4(const unsigned short* __restrict__ encb,
                           const float* __restrict__ sp, float* __restrict__ out) {
    int b  = blockIdx.y;
    int sc = blockIdx.x;
    int t  = threadIdx.x;
    __shared__ float red[4];
    __shared__ float w[256];

    const float* p = sp + (size_t)b * SEQ;

    // pass 1: max over 2048 summed scores
    float lmax = -1e30f;
    float loc[8];
    #pragma unroll
    for (int k = 0; k < 8; ++k) {
        int i = k * 256 + t;
        float v = p[i] + p[i + ROWS];
        loc[k] = v;
        lmax = fmaxf(lmax, v);
    }
    for (int m = 1; m < 64; m <<= 1) lmax = fmaxf(lmax, __shfl_xor(lmax, m));
    if ((t & 63) == 0) red[t >> 6] = lmax;
    __syncthreads();
    float gmax = fmaxf(fmaxf(red[0], red[1]), fmaxf(red[2], red[3]));
    __syncthreads();

    // pass 2: sum of exp
    float lsum = 0.0f;
    #pragma unroll
    for (int k = 0; k < 8; ++k) lsum += __expf(loc[k] - gmax);
    for (int m = 1; m < 64; m <<= 1) lsum += __shfl_xor(lsum, m);
    if ((t & 63) == 0) red[t >> 6] = lsum;
    __syncthreads();
    float inv = 1.0f / (red[0] + red[1] + red[2] + red[3]);

    // weights for my 256-row chunk
    {
        int i = sc * 256 + t;
        float v = p[i] + p[i + ROWS];
        w[t] = __expf(v - gmax) * inv;
    }
    __syncthreads();

    // stream: thread t owns cols 2t, 2t+1
    const unsigned short* e = encb + ((size_t)b * SEQ + sc * 256) * HID + t * 2;
    float ax = 0.0f, ay = 0.0f;
    #pragma unroll 8
    for (int s = 0; s < 256; ++s) {
        float ws = w[s];
        unsigned int v = *(const unsigned int*)(e + (size_t)s * HID);
        ax += ws * bf16lo(v);
        ay += ws * bf16hi(v);
    }
    atomicAdd(&out[b * HID + t * 2], ax);
    atomicAdd(&out[b * HID + t * 2 + 1], ay);
}

// ================= fallback path (fp32 in-kernel cvt, small ws) =================
#define BK  64
#define LDA 72

__global__ __launch_bounds__(256) void k_energy_fb(
        const float* __restrict__ enc, const float* __restrict__ attw,
        const float* __restrict__ cbuf, const float* __restrict__ vw,
        float* __restrict__ scores) {
    __shared__ __align__(16) unsigned short As[128 * LDA];
    __shared__ __align__(16) unsigned short Bs[128 * LDA];
    const int nTile = blockIdx.x * 128;
    const int sRow  = blockIdx.y * 128;
    const int bIdx  = sRow >> 11;
    const int t = threadIdx.x, lane = t & 63, wave = t >> 6;
    const int wm = wave >> 1, wn = wave & 1, l16 = lane & 15, q = lane >> 4;
    const int tr = t >> 3, tc = (t & 7) * 8;

    f32x4 acc[4][4];
    #pragma unroll
    for (int i = 0; i < 4; ++i)
        #pragma unroll
        for (int j = 0; j < 4; ++j) acc[i][j] = (f32x4){0.f, 0.f, 0.f, 0.f};

    for (int h0 = 0; h0 < HID; h0 += BK) {
        #pragma unroll
        for (int i = 0; i < 4; ++i) {
            int row = tr + i * 32;
            const float* gA = enc + (size_t)(sRow + row) * HID + h0 + tc;
            float4 a0 = *(const float4*)gA;
            float4 a1 = *(const float4*)(gA + 4);
            uint4 pa = {cvt2_bf16(a0.x, a0.y), cvt2_bf16(a0.z, a0.w),
                        cvt2_bf16(a1.x, a1.y), cvt2_bf16(a1.z, a1.w)};
            *(uint4*)(&As[row * LDA + tc]) = pa;
            const float* gB = attw + (size_t)(nTile + row) * (2 * HID) + h0 + tc;
            float4 b0 = *(const float4*)gB;
            float4 b1 = *(const float4*)(gB + 4);
            uint4 pb = {cvt2_bf16(b0.x, b0.y), cvt2_bf16(b0.z, b0.w),
                        cvt2_bf16(b1.x, b1.y), cvt2_bf16(b1.z, b1.w)};
            *(uint4*)(&Bs[row * LDA + tc]) = pb;
        }
        __syncthreads();
        #pragma unroll
        for (int kk = 0; kk < BK; kk += 32) {
            short8 af[4], bf[4];
            #pragma unroll
            for (int i = 0; i < 4; ++i)
                af[i] = *(const short8*)(&As[(wm * 64 + i * 16 + l16) * LDA + kk + q * 8]);
            #pragma unroll
            for (int j = 0; j < 4; ++j)
                bf[j] = *(const short8*)(&Bs[(wn * 64 + j * 16 + l16) * LDA + kk + q * 8]);
            #pragma unroll
            for (int i = 0; i < 4; ++i)
                #pragma unroll
                for (int j = 0; j < 4; ++j)
                    acc[i][j] = __builtin_amdgcn_mfma_f32_16x16x32_bf16(
                        af[i], bf[j], acc[i][j], 0, 0, 0);
        }
        __syncthreads();
    }
    #pragma unroll
    for (int i = 0; i < 4; ++i) {
        #pragma unroll
        for (int r = 0; r < 4; ++r) {
            float sum = 0.0f;
            #pragma unroll
            for (int j = 0; j < 4; ++j) {
                int colg = nTile + wn * 64 + j * 16 + l16;
                sum += fast_tanh(acc[i][j][r] + cbuf[bIdx * HID + colg]) * vw[colg];
            }
            sum += __shfl_xor(sum, 1);
            sum += __shfl_xor(sum, 2);
            sum += __shfl_xor(sum, 4);
            sum += __shfl_xor(sum, 8);
            if (l16 == 0) atomicAdd(&scores[sRow + wm * 64 + i * 16 + q * 4 + r], sum);
        }
    }
}

__global__ void k_softmax(float* __restrict__ sw) {
    int b = blockIdx.x;
    float* s = sw + (size_t)b * SEQ;
    int t = threadIdx.x;
    __shared__ float red[4];
    float lmax = -1e30f;
    for (int i = t; i < SEQ; i += 256) lmax = fmaxf(lmax, s[i]);
    for (int m = 1; m < 64; m <<= 1) lmax = fmaxf(lmax, __shfl_xor(lmax, m));
    if ((t & 63) == 0) red[t >> 6] = lmax;
    __syncthreads();
    float gmax = fmaxf(fmaxf(red[0], red[1]), fmaxf(red[2], red[3]));
    __syncthreads();
    float lsum = 0.0f;
    for (int i = t; i < SEQ; i += 256) lsum += __expf(s[i] - gmax);
    for (int m = 1; m < 64; m <<= 1) lsum += __shfl_xor(lsum, m);
    if ((t & 63) == 0) red[t >> 6] = lsum;
    __syncthreads();
    float inv = 1.0f / (red[0] + red[1] + red[2] + red[3]);
    for (int i = t; i < SEQ; i += 256) s[i] = __expf(s[i] - gmax) * inv;
}

__global__ void k_fin_fb(const float* __restrict__ fin, const float* __restrict__ attw,
                         const float* __restrict__ attb, float* __restrict__ cbuf) {
    int b  = blockIdx.y;
    int k  = blockIdx.x * 32 + (threadIdx.x >> 3);
    int l8 = threadIdx.x & 7;
    const float* f = fin + b * HID;
    const float* w = attw + (size_t)k * (2 * HID) + HID;
    float s = 0.0f;
    for (int h = l8 * 4; h < HID; h += 32) {
        float4 a  = *(const float4*)(f + h);
        float4 ww = *(const float4*)(w + h);
        s += a.x * ww.x + a.y * ww.y + a.z * ww.z + a.w * ww.w;
    }
    s += __shfl_xor(s, 1);
    s += __shfl_xor(s, 2);
    s += __shfl_xor(s, 4);
    if (l8 == 0) cbuf[b * HID + k] = s + attb[k];
}

__global__ void k_context_fb(const float* __restrict__ enc, const float* __restrict__ wts,
                             float* __restrict__ out) {
    int b = blockIdx.y, sc = blockIdx.x, t = threadIdx.x;
    const float* e = enc + ((size_t)b * SEQ + sc * 128) * HID + t * 2;
    const float* w = wts + (size_t)b * SEQ + sc * 128;
    float ax = 0.f, ay = 0.f;
    #pragma unroll 4
    for (int s = 0; s < 128; ++s) {
        float ws = w[s];
        float2 v = *(const float2*)(e + (size_t)s * HID);
        ax += ws * v.x;
        ay += ws * v.y;
    }
    atomicAdd(&out[b * HID + t * 2], ax);
    atomicAdd(&out[b * HID + t * 2 + 1], ay);
}

extern "C" void kernel_launch(void* const* d_in, const int* in_sizes, int n_in,
                              void* d_out, int out_size, void* d_ws, size_t ws_size,
                              hipStream_t stream) {
    const float* enc  = (const float*)d_in[0];
    const float* fin  = (const float*)d_in[1];
    const float* attw = (const float*)d_in[2];
    const float* attb = (const float*)d_in[3];
    const float* vw   = (const float*)d_in[4];
    float* out = (float*)d_out;

    char* ws = (char*)d_ws;
    float* cbuf = (float*)ws;                                   // 131072 B
    float* sp   = (float*)(ws + 131072);                        // 2*524288 B partial scores
    unsigned short* wb   = (unsigned short*)(ws + 131072 + 2 * 524288);   // 524288 B
    unsigned short* encb = (unsigned short*)(ws + 131072 + 3 * 524288);   // 134217728 B
    const size_t need = 131072ull + 3 * 524288 + 134217728;

    hipMemsetAsync(out, 0, (size_t)BATCH * HID * sizeof(float), stream);

    if (ws_size >= need) {
        k_prep<<<PREP_GRID, 256, 0, stream>>>(enc, attw, attb, fin, encb, wb, cbuf);
        k_energy4<<<dim3(2, ROWS / 128), 256, 0, stream>>>(encb, wb, cbuf, vw, sp);
        k_context4<<<dim3(8, 64), 256, 0, stream>>>(encb, sp, out);
    } else {
        hipMemsetAsync(sp, 0, (size_t)ROWS * sizeof(float), stream);
        k_fin_fb<<<dim3(16, 64), 256, 0, stream>>>(fin, attw, attb, cbuf);
        k_energy_fb<<<dim3(4, ROWS / 128), 256, 0, stream>>>(enc, attw, cbuf, vw, sp);
        k_softmax<<<BATCH, 256, 0, stream>>>(sp);
        k_context_fb<<<dim3(16, 64), 256, 0, stream>>>(enc, sp, out);
    }
}